// Round 13
// baseline (420.764 us; speedup 1.0000x reference)
//
#include <hip/hip_runtime.h>
#include <hip/hip_bf16.h>
#include <hip/hip_cooperative_groups.h>

namespace cg = cooperative_groups;

#define N 8192
#define D 128
#define LOG2E  1.44269504088896f
#define LN2    0.69314718055995f
#define NBLK   512                 // persistent blocks (2/CU, cooperative)
#define NTILE  2080                // 64*65/2 triangular 128x128 tiles

typedef __attribute__((ext_vector_type(8))) short bf16x8;
typedef __attribute__((ext_vector_type(4))) float f32x4;

#if __has_builtin(__builtin_amdgcn_exp2f)
#define EXP2(x) __builtin_amdgcn_exp2f(x)
#else
#define EXP2(x) exp2f(x)
#endif
#if __has_builtin(__builtin_amdgcn_logf)
#define LOG2(x) __builtin_amdgcn_logf(x)
#else
#define LOG2(x) log2f(x)
#endif

static __device__ __forceinline__ unsigned short f2bf(float f) {
    union { float f; unsigned int u; } x;
    x.f = f;
    unsigned int r = ((x.u >> 16) & 1u) + 0x7FFFu;  // round-to-nearest-even
    return (unsigned short)((x.u + r) >> 16);
}

// R13: ONE persistent cooperative kernel (prep -> tiles -> finalize).
// R12 post-mortem: register prefetch neutral -> in-loop latency exonerated.
// Remaining suspects are dispatch-side: 2080 short blocks x per-block
// head/tail over ~3 dispatch generations + 2 inter-kernel launch gaps
// (residual ~13us every round). This kernel makes the whole workload one
// dispatch: 512 blocks (2/CU guaranteed co-resident by cooperative launch),
// each handles ~4 tiles; grid.sync + device fences between phases
// (release-wb / acquire-inv, pattern validated by R9's ticket).
// Tile body = R11 verbatim (fragment-major Eb2, zero-amplification 1-KB
// wave-loads, triangular symmetry, plane stores, no global atomics).
// Lessons kept: loops pinned rolled (R4), no min-waves bound (R2).
__global__ __launch_bounds__(256) void mega_kernel(
        const float* __restrict__ E,
        const int* __restrict__ labels,
        unsigned short* __restrict__ Eb2,
        float* __restrict__ part,
        float* __restrict__ bpart,
        float* __restrict__ out) {
    cg::grid_group grid = cg::this_grid();
    __shared__ int   labC[128];
    __shared__ int   labR[128];
    __shared__ float colacc[128];
    __shared__ float red[4];

    const int tid  = threadIdx.x;
    const int bid  = blockIdx.x;
    const int wid  = tid >> 6;     // 0..3
    const int lane = tid & 63;
    const int q = lane >> 4;       // 0..3
    const int l = lane & 15;       // 0..15

    // ---- phase 1: E (fp32) -> Eb2 (bf16) fragment-major ----
    // chunk (S,kk,lane) at byte S*4096 + kk*1024 + lane*16; 131072 chunks,
    // exactly one per thread.
    {
        const int j = bid * 256 + tid;
        const int pl  = j & 15;
        const int pq  = (j >> 4) & 3;
        const int pkk = (j >> 6) & 3;
        const int pS  = j >> 8;
        const float4* src = (const float4*)(E + (size_t)(pS * 16 + pl) * D + pkk * 32 + pq * 8);
        float4 f0 = src[0], f1 = src[1];
        uint4 o;
        o.x = f2bf(f0.x) | ((unsigned)f2bf(f0.y) << 16);
        o.y = f2bf(f0.z) | ((unsigned)f2bf(f0.w) << 16);
        o.z = f2bf(f1.x) | ((unsigned)f2bf(f1.y) << 16);
        o.w = f2bf(f1.z) | ((unsigned)f2bf(f1.w) << 16);
        ((uint4*)Eb2)[j] = o;
    }
    __threadfence();     // release: write back Eb2 to device-coherent point
    grid.sync();
    __threadfence();     // acquire: invalidate stale L1/L2

    const char* base = (const char*)Eb2;

    // ---- phase 2: persistent sweep over triangular tiles ----
#pragma clang loop unroll(disable)
    for (int t = bid; t < NTILE; t += NBLK) {
        // decode t -> (r, c), r <= c
        int r = (int)(64.5f - sqrtf(64.5f * 64.5f - 2.0f * (float)t));
        while ((r + 1) * 64 - ((r + 1) * r) / 2 <= t) ++r;
        while (r * 64 - (r * (r - 1)) / 2 > t) --r;
        const int c = r + (t - (r * 64 - (r * (r - 1)) / 2));
        const bool diag = (r == c);
        const int tile_m0 = r * 128;
        const int n_begin = c * 128;
        const int mrow0 = wid * 32;

        // A fragments: contiguous 1-KB wave-loads.
        bf16x8 a[2][4];
#pragma unroll
        for (int g = 0; g < 2; ++g) {
            const char* pa = base + (size_t)(r * 8 + wid * 2 + g) * 4096 + lane * 16;
#pragma unroll
            for (int kk = 0; kk < 4; ++kk)
                a[g][kk] = *(const bf16x8*)(pa + kk * 1024);
        }

        if (tid < 128) { labC[tid] = labels[n_begin + tid]; colacc[tid] = 0.0f; }
        else           { labR[tid - 128] = labels[tile_m0 + (tid - 128)]; }
        __syncthreads();

        int lrow[8];
#pragma unroll
        for (int g = 0; g < 2; ++g)
#pragma unroll
            for (int rr = 0; rr < 4; ++rr)
                lrow[g * 4 + rr] = labR[mrow0 + g * 16 + q * 4 + rr];

        float sum[8];
#pragma unroll
        for (int i = 0; i < 8; ++i) sum[i] = 0.0f;

#pragma clang loop unroll(disable)
        for (int s = 0; s < 8; ++s) {
            const char* pb = base + (size_t)(c * 8 + s) * 4096 + lane * 16;
            bf16x8 b0 = *(const bf16x8*)(pb);
            bf16x8 b1 = *(const bf16x8*)(pb + 1024);
            bf16x8 b2 = *(const bf16x8*)(pb + 2048);
            bf16x8 b3 = *(const bf16x8*)(pb + 3072);
            const int lc = labC[s * 16 + l];

            f32x4 acc0 = (f32x4){0.f, 0.f, 0.f, 0.f};
            f32x4 acc1 = (f32x4){0.f, 0.f, 0.f, 0.f};
            acc0 = __builtin_amdgcn_mfma_f32_16x16x32_bf16(a[0][0], b0, acc0, 0, 0, 0);
            acc0 = __builtin_amdgcn_mfma_f32_16x16x32_bf16(a[0][1], b1, acc0, 0, 0, 0);
            acc0 = __builtin_amdgcn_mfma_f32_16x16x32_bf16(a[0][2], b2, acc0, 0, 0, 0);
            acc0 = __builtin_amdgcn_mfma_f32_16x16x32_bf16(a[0][3], b3, acc0, 0, 0, 0);
            acc1 = __builtin_amdgcn_mfma_f32_16x16x32_bf16(a[1][0], b0, acc1, 0, 0, 0);
            acc1 = __builtin_amdgcn_mfma_f32_16x16x32_bf16(a[1][1], b1, acc1, 0, 0, 0);
            acc1 = __builtin_amdgcn_mfma_f32_16x16x32_bf16(a[1][2], b2, acc1, 0, 0, 0);
            acc1 = __builtin_amdgcn_mfma_f32_16x16x32_bf16(a[1][3], b3, acc1, 0, 0, 0);

            float cp = 0.0f;
#pragma unroll
            for (int g = 0; g < 2; ++g) {
#pragma unroll
                for (int rr = 0; rr < 4; ++rr) {
                    float sv = (g == 0) ? acc0[rr] : acc1[rr];
                    bool eq = (lrow[g * 4 + rr] == lc);
                    float cc = eq ? -LOG2E : LOG2E;
                    float term = EXP2(cc * (sv - 0.1f));
                    sum[g * 4 + rr] += term;
                    cp += term;
                }
            }
            if (!diag) {
                cp += __shfl_xor(cp, 16);
                cp += __shfl_xor(cp, 32);
                if (q == 0) atomicAdd(&colacc[s * 16 + l], cp);  // LDS only
            }
        }

        // Row credits -> plane c (plain stores).
#pragma unroll
        for (int i = 0; i < 8; ++i) {
            float v = sum[i];
            v += __shfl_xor(v, 1);
            v += __shfl_xor(v, 2);
            v += __shfl_xor(v, 4);
            v += __shfl_xor(v, 8);
            sum[i] = v;
        }
        if (l == 0) {
#pragma unroll
            for (int g = 0; g < 2; ++g)
#pragma unroll
                for (int rr = 0; rr < 4; ++rr)
                    part[(size_t)c * N + tile_m0 + mrow0 + g * 16 + q * 4 + rr] = sum[g * 4 + rr];
        }

        __syncthreads();   // colacc complete; also guards next-iter reuse
        if (!diag && tid < 128)
            part[(size_t)r * N + n_begin + tid] = colacc[tid];
    }
    __threadfence();
    grid.sync();
    __threadfence();

    // ---- phase 3: rowsum over 64 planes -> log -> 32 block partials ----
    if (bid < 32) {
        const int i = bid * 256 + tid;
        float s = 0.0f;
#pragma unroll 8
        for (int x = 0; x < 64; ++x) s += part[(size_t)x * N + i];
        float v = LOG2(s) * LN2;
#pragma unroll
        for (int off = 1; off <= 32; off <<= 1) v += __shfl_xor(v, off);
        if ((tid & 63) == 0) red[tid >> 6] = v;
        __syncthreads();
        if (tid == 0) bpart[bid] = red[0] + red[1] + red[2] + red[3];
    }
    __threadfence();
    grid.sync();

    // ---- phase 4: final scalar ----
    if (bid == 0 && tid < 64) {
        float tv = (tid < 32)
            ? __hip_atomic_load(&bpart[tid], __ATOMIC_RELAXED, __HIP_MEMORY_SCOPE_AGENT)
            : 0.0f;
#pragma unroll
        for (int off = 1; off <= 32; off <<= 1) tv += __shfl_xor(tv, off);
        if (tid == 0) out[0] = tv * (1.0f / (float)N);
    }
}

extern "C" void kernel_launch(void* const* d_in, const int* in_sizes, int n_in,
                              void* d_out, int out_size, void* d_ws, size_t ws_size,
                              hipStream_t stream) {
    const float* E = (const float*)d_in[0];
    const int* labels = (const int*)d_in[1];
    float* out = (float*)d_out;

    unsigned short* Eb2 = (unsigned short*)d_ws;                // 2 MiB fragment-major
    float* part = (float*)((char*)d_ws + (size_t)N * D * 2);    // 64*8192*4 = 2 MiB
    float* bpart = part + (size_t)64 * N;                       // 32 floats

    void* args[] = {(void*)&E, (void*)&labels, (void*)&Eb2,
                    (void*)&part, (void*)&bpart, (void*)&out};
    hipLaunchCooperativeKernel((const void*)mega_kernel,
                               dim3(NBLK), dim3(256), args, 0, stream);
}

// Round 14
// 86.765 us; speedup vs baseline: 4.8495x; 4.8495x over previous
//
#include <hip/hip_runtime.h>
#include <hip/hip_bf16.h>

#define N 8192
#define D 128
#define LOG2E  1.44269504088896f
#define LN2    0.69314718055995f
#define NPLANE 32                  // 32 row-tiles of 256 rows

typedef __attribute__((ext_vector_type(8))) short bf16x8;
typedef __attribute__((ext_vector_type(4))) float f32x4;

#if __has_builtin(__builtin_amdgcn_exp2f)
#define EXP2(x) __builtin_amdgcn_exp2f(x)
#else
#define EXP2(x) exp2f(x)
#endif
#if __has_builtin(__builtin_amdgcn_logf)
#define LOG2(x) __builtin_amdgcn_logf(x)
#else
#define LOG2(x) log2f(x)
#endif

static __device__ __forceinline__ unsigned short f2bf(float f) {
    union { float f; unsigned int u; } x;
    x.f = f;
    unsigned int r = ((x.u >> 16) & 1u) + 0x7FFFu;  // round-to-nearest-even
    return (unsigned short)((x.u + r) >> 16);
}

// Kernel 1 (R11): E (fp32) -> Eb2 (bf16) in FRAGMENT-MAJOR layout.
// Chunk (S,kk,lane) at byte S*4096 + kk*1024 + lane*16 -> every MFMA frag
// load in fused is ONE contiguous 1-KB wave-load (zero amplification).
__global__ void prep_kernel(const float* __restrict__ E,
                            uint4* __restrict__ Eb2,
                            unsigned int* __restrict__ counter) {
    const int j = blockIdx.x * 256 + threadIdx.x;   // 0..131071
    const int l  = j & 15;
    const int q  = (j >> 4) & 3;
    const int kk = (j >> 6) & 3;
    const int S  = j >> 8;
    const float4* src = (const float4*)(E + (size_t)(S * 16 + l) * D + kk * 32 + q * 8);
    float4 f0 = src[0], f1 = src[1];
    uint4 o;
    o.x = f2bf(f0.x) | ((unsigned)f2bf(f0.y) << 16);
    o.y = f2bf(f0.z) | ((unsigned)f2bf(f0.w) << 16);
    o.z = f2bf(f1.x) | ((unsigned)f2bf(f1.y) << 16);
    o.w = f2bf(f1.z) | ((unsigned)f2bf(f1.w) << 16);
    Eb2[j] = o;
    if (j == 0) *counter = 0u;
}

// Kernel 2 (R14): 256x256 TILES — amortize per-block head/tail, 4:1
// MFMA:B-load ratio. R13's cooperative fusion was a disaster (grid.sync
// ~100us+/sync on 512 blocks); reverted to R11 3-kernel structure.
// 528 triangular blocks (32x33/2), 4 waves x 64 rows (a[4][4] reused over
// 16 subtiles of 16 cols). One f32x4 acc live at a time keeps VGPR ~150.
// Lessons kept: loops pinned rolled (R4), no min-waves bound (R2), plane
// stores / no global atomics (R9), fragment-major direct loads (R11),
// no register prefetch (R12 neutral).
__global__ __launch_bounds__(256) void fused_kernel(
        const unsigned short* __restrict__ Eb2,
        const int* __restrict__ labels,
        float* __restrict__ part) {
    __shared__ int   labC[256];
    __shared__ int   labR[256];
    __shared__ float colacc[256];

    const int tid  = threadIdx.x;
    const int wid  = tid >> 6;     // 0..3
    const int lane = tid & 63;
    const int q = lane >> 4;       // 0..3
    const int l = lane & 15;       // 0..15

    // Triangular tile decode b -> (r, c), r <= c, 32 row-tiles (256 wide).
    const int b = blockIdx.x;
    int r = (int)(32.5f - sqrtf(32.5f * 32.5f - 2.0f * (float)b));
    while ((r + 1) * 32 - ((r + 1) * r) / 2 <= b) ++r;
    while (r * 32 - (r * (r - 1)) / 2 > b) --r;
    const int c = r + (b - (r * 32 - (r * (r - 1)) / 2));
    const bool diag = (r == c);
    const int tile_m0 = r * 256;
    const int n_begin = c * 256;
    const int mrow0 = wid * 64;            // wave's row strip within tile

    const char* base = (const char*)Eb2;

    // A fragments: row-group S_A = r*16 + wid*4 + g. Contiguous 1-KB loads.
    bf16x8 a[4][4];
#pragma unroll
    for (int g = 0; g < 4; ++g) {
        const char* pa = base + (size_t)(r * 16 + wid * 4 + g) * 4096 + lane * 16;
#pragma unroll
        for (int kk = 0; kk < 4; ++kk)
            a[g][kk] = *(const bf16x8*)(pa + kk * 1024);
    }

    labC[tid] = labels[n_begin + tid];
    labR[tid] = labels[tile_m0 + tid];
    colacc[tid] = 0.0f;
    __syncthreads();

    int lrow[16];
#pragma unroll
    for (int g = 0; g < 4; ++g)
#pragma unroll
        for (int rr = 0; rr < 4; ++rr)
            lrow[g * 4 + rr] = labR[mrow0 + g * 16 + q * 4 + rr];

    float sum[16];
#pragma unroll
    for (int i = 0; i < 16; ++i) sum[i] = 0.0f;

    // ---- compute: 16 subtiles of 16 cols; B frags direct from Eb2 ----
#pragma clang loop unroll(disable)
    for (int s = 0; s < 16; ++s) {
        const char* pb = base + (size_t)(c * 16 + s) * 4096 + lane * 16;
        bf16x8 b0 = *(const bf16x8*)(pb);
        bf16x8 b1 = *(const bf16x8*)(pb + 1024);
        bf16x8 b2 = *(const bf16x8*)(pb + 2048);
        bf16x8 b3 = *(const bf16x8*)(pb + 3072);
        const int lc = labC[s * 16 + l];

        float cp = 0.0f;
#pragma unroll
        for (int g = 0; g < 4; ++g) {
            f32x4 acc = (f32x4){0.f, 0.f, 0.f, 0.f};
            acc = __builtin_amdgcn_mfma_f32_16x16x32_bf16(a[g][0], b0, acc, 0, 0, 0);
            acc = __builtin_amdgcn_mfma_f32_16x16x32_bf16(a[g][1], b1, acc, 0, 0, 0);
            acc = __builtin_amdgcn_mfma_f32_16x16x32_bf16(a[g][2], b2, acc, 0, 0, 0);
            acc = __builtin_amdgcn_mfma_f32_16x16x32_bf16(a[g][3], b3, acc, 0, 0, 0);
#pragma unroll
            for (int rr = 0; rr < 4; ++rr) {
                float sv = acc[rr];
                bool eq = (lrow[g * 4 + rr] == lc);
                float cc = eq ? -LOG2E : LOG2E;
                float term = EXP2(cc * (sv - 0.1f));
                sum[g * 4 + rr] += term;
                cp += term;
            }
        }
        if (!diag) {
            cp += __shfl_xor(cp, 16);   // reduce over q-quarters
            cp += __shfl_xor(cp, 32);
            if (q == 0) atomicAdd(&colacc[s * 16 + l], cp);  // LDS only
        }
    }

    // Row credits: reduce across the 16 column-lanes, PLAIN stores, plane c.
#pragma unroll
    for (int i = 0; i < 16; ++i) {
        float v = sum[i];
        v += __shfl_xor(v, 1);
        v += __shfl_xor(v, 2);
        v += __shfl_xor(v, 4);
        v += __shfl_xor(v, 8);
        sum[i] = v;
    }
    if (l == 0) {
#pragma unroll
        for (int g = 0; g < 4; ++g)
#pragma unroll
            for (int rr = 0; rr < 4; ++rr)
                part[(size_t)c * N + tile_m0 + mrow0 + g * 16 + q * 4 + rr] = sum[g * 4 + rr];
    }

    // Col credits: PLAIN stores to plane r (off-diagonal only).
    __syncthreads();
    if (!diag)
        part[(size_t)r * N + n_begin + tid] = colacc[tid];
}

// Kernel 3: rowsum_i = sum over 32 planes; log; block-reduce; ticketed final.
__global__ void finalize_kernel(const float* __restrict__ part,
                                float* __restrict__ bpart,
                                unsigned int* __restrict__ counter,
                                float* __restrict__ out) {
    __shared__ float red[4];
    __shared__ unsigned int tk;
    const int tid = threadIdx.x;
    const int i = blockIdx.x * 256 + tid;

    float s = 0.0f;
#pragma unroll 8
    for (int x = 0; x < NPLANE; ++x) s += part[(size_t)x * N + i];
    float v = LOG2(s) * LN2;
#pragma unroll
    for (int off = 1; off <= 32; off <<= 1) v += __shfl_xor(v, off);
    if ((tid & 63) == 0) red[tid >> 6] = v;
    __syncthreads();
    if (tid == 0) {
        bpart[blockIdx.x] = red[0] + red[1] + red[2] + red[3];
        __threadfence();                       // release bpart store
        tk = atomicAdd(counter, 1u);
    }
    __syncthreads();
    if (tk == 31u) {                           // last block finalizes
        __threadfence();                       // acquire
        if (tid < 64) {
            float t = (tid < 32)
                ? __hip_atomic_load(&bpart[tid], __ATOMIC_RELAXED,
                                    __HIP_MEMORY_SCOPE_AGENT)
                : 0.0f;
#pragma unroll
            for (int off = 1; off <= 32; off <<= 1) t += __shfl_xor(t, off);
            if (tid == 0) out[0] = t * (1.0f / (float)N);
        }
    }
}

extern "C" void kernel_launch(void* const* d_in, const int* in_sizes, int n_in,
                              void* d_out, int out_size, void* d_ws, size_t ws_size,
                              hipStream_t stream) {
    const float* E = (const float*)d_in[0];
    const int* labels = (const int*)d_in[1];
    float* out = (float*)d_out;

    unsigned short* Eb2 = (unsigned short*)d_ws;                // 2 MiB, fragment-major
    float* part = (float*)((char*)d_ws + (size_t)N * D * 2);    // 32*8192*4 = 1 MiB
    float* bpart = part + (size_t)NPLANE * N;                   // 32 floats
    unsigned int* counter = (unsigned int*)(bpart + 32);        // 4 B

    prep_kernel<<<512, 256, 0, stream>>>(E, (uint4*)Eb2, counter);
    fused_kernel<<<528, 256, 0, stream>>>(Eb2, labels, part);
    finalize_kernel<<<32, 256, 0, stream>>>(part, bpart, counter, out);
}